// Round 1
// baseline (587.809 us; speedup 1.0000x reference)
//
#include <hip/hip_runtime.h>

#define B_ 4
#define N_ 2048
#define H_ 8
#define C_ 768
#define CV_ 512
#define DH_ 96
#define DV_ 64
#define SCALE_ 0.17677669529663687f

using bf16x8 = __attribute__((ext_vector_type(8))) short;
using f32x4  = __attribute__((ext_vector_type(4))) float;
using u16x4  = __attribute__((ext_vector_type(4))) unsigned short;

__device__ __forceinline__ unsigned short f2bf(float f) {
  union { float f; unsigned u; } x; x.f = f;
  unsigned r = x.u + 0x7fffu + ((x.u >> 16) & 1u);
  return (unsigned short)(r >> 16);
}
__device__ __forceinline__ float bf2f(unsigned short b) {
  union { unsigned u; float f; } x; x.u = ((unsigned)b) << 16;
  return x.f;
}

#define MFMA(a,b,c) __builtin_amdgcn_mfma_f32_16x16x32_bf16((a),(b),(c),0,0,0)

// ---------------------------------------------------------------------------
// Split-precision projection: O = X @ W^T, X:(8192,768), W:(768,768)
// Output stored as bf16 hi+lo at [(b*8+h)*2048+n]*96 + d  (h=co/96, d=co%96)
// ---------------------------------------------------------------------------
__global__ __launch_bounds__(256) void proj_split_kernel(
    const float* __restrict__ X, const float* __restrict__ W,
    unsigned short* __restrict__ Ohi, unsigned short* __restrict__ Olo)
{
  __shared__ __align__(16) unsigned short Ah[64][72];
  __shared__ __align__(16) unsigned short Al[64][72];
  __shared__ __align__(16) unsigned short Bh[64][72];
  __shared__ __align__(16) unsigned short Bl[64][72];

  const int mb = blockIdx.x * 64;
  const int nb = blockIdx.y * 64;
  const int t = threadIdx.x;
  const int wave = t >> 6;
  const int lane = t & 63;
  const int fr = lane & 15;
  const int kof = (lane >> 4) * 8;

  f32x4 acc[4];
#pragma unroll
  for (int i = 0; i < 4; ++i) acc[i] = (f32x4){0.f, 0.f, 0.f, 0.f};

  for (int kb = 0; kb < C_; kb += 64) {
    __syncthreads();
#pragma unroll
    for (int i = 0; i < 4; ++i) {
      int c = t + 256 * i;
      int r = c >> 4;
      int c4 = (c & 15) * 4;
      float4 xa = *(const float4*)(X + (size_t)(mb + r) * C_ + kb + c4);
      float4 xb = *(const float4*)(W + (size_t)(nb + r) * C_ + kb + c4);
      float va[4] = {xa.x, xa.y, xa.z, xa.w};
      float vb[4] = {xb.x, xb.y, xb.z, xb.w};
      u16x4 ah, al, bh, bl;
#pragma unroll
      for (int j = 0; j < 4; ++j) {
        unsigned short hi = f2bf(va[j]); ah[j] = hi; al[j] = f2bf(va[j] - bf2f(hi));
        unsigned short hj = f2bf(vb[j]); bh[j] = hj; bl[j] = f2bf(vb[j] - bf2f(hj));
      }
      *(u16x4*)&Ah[r][c4] = ah; *(u16x4*)&Al[r][c4] = al;
      *(u16x4*)&Bh[r][c4] = bh; *(u16x4*)&Bl[r][c4] = bl;
    }
    __syncthreads();
#pragma unroll
    for (int s = 0; s < 2; ++s) {
      bf16x8 a_h = *(const bf16x8*)&Ah[wave * 16 + fr][s * 32 + kof];
      bf16x8 a_l = *(const bf16x8*)&Al[wave * 16 + fr][s * 32 + kof];
#pragma unroll
      for (int nt = 0; nt < 4; ++nt) {
        bf16x8 b_h = *(const bf16x8*)&Bh[nt * 16 + fr][s * 32 + kof];
        bf16x8 b_l = *(const bf16x8*)&Bl[nt * 16 + fr][s * 32 + kof];
        acc[nt] = MFMA(a_h, b_h, acc[nt]);
        acc[nt] = MFMA(a_h, b_l, acc[nt]);
        acc[nt] = MFMA(a_l, b_h, acc[nt]);
      }
    }
  }
#pragma unroll
  for (int nt = 0; nt < 4; ++nt) {
#pragma unroll
    for (int r = 0; r < 4; ++r) {
      int m = mb + wave * 16 + (lane >> 4) * 4 + r;
      int co = nb + nt * 16 + fr;
      int b = m >> 11, n = m & (N_ - 1);
      int h = co / DH_, d = co % DH_;
      size_t idx = ((size_t)((b * H_ + h) * N_ + n)) * DH_ + d;
      float vv = acc[nt][r];
      unsigned short hi = f2bf(vv);
      Ohi[idx] = hi;
      Olo[idx] = f2bf(vv - bf2f(hi));
    }
  }
}

// ---------------------------------------------------------------------------
// Single-bf16 projection for V: O = X @ W^T, X:(8192,512), W:(512,512)
// Output bf16 at [(b*8+h)*2048+n]*64 + d
// ---------------------------------------------------------------------------
__global__ __launch_bounds__(256) void proj_v_kernel(
    const float* __restrict__ X, const float* __restrict__ W,
    unsigned short* __restrict__ Ov)
{
  __shared__ __align__(16) unsigned short As[64][72];
  __shared__ __align__(16) unsigned short Bs[64][72];

  const int mb = blockIdx.x * 64;
  const int nb = blockIdx.y * 64;
  const int t = threadIdx.x;
  const int wave = t >> 6;
  const int lane = t & 63;
  const int fr = lane & 15;
  const int kof = (lane >> 4) * 8;

  f32x4 acc[4];
#pragma unroll
  for (int i = 0; i < 4; ++i) acc[i] = (f32x4){0.f, 0.f, 0.f, 0.f};

  for (int kb = 0; kb < CV_; kb += 64) {
    __syncthreads();
#pragma unroll
    for (int i = 0; i < 4; ++i) {
      int c = t + 256 * i;
      int r = c >> 4;
      int c4 = (c & 15) * 4;
      float4 xa = *(const float4*)(X + (size_t)(mb + r) * CV_ + kb + c4);
      float4 xb = *(const float4*)(W + (size_t)(nb + r) * CV_ + kb + c4);
      u16x4 ah, bh;
      ah[0] = f2bf(xa.x); ah[1] = f2bf(xa.y); ah[2] = f2bf(xa.z); ah[3] = f2bf(xa.w);
      bh[0] = f2bf(xb.x); bh[1] = f2bf(xb.y); bh[2] = f2bf(xb.z); bh[3] = f2bf(xb.w);
      *(u16x4*)&As[r][c4] = ah;
      *(u16x4*)&Bs[r][c4] = bh;
    }
    __syncthreads();
#pragma unroll
    for (int s = 0; s < 2; ++s) {
      bf16x8 a8 = *(const bf16x8*)&As[wave * 16 + fr][s * 32 + kof];
#pragma unroll
      for (int nt = 0; nt < 4; ++nt) {
        bf16x8 b8 = *(const bf16x8*)&Bs[nt * 16 + fr][s * 32 + kof];
        acc[nt] = MFMA(a8, b8, acc[nt]);
      }
    }
  }
#pragma unroll
  for (int nt = 0; nt < 4; ++nt) {
#pragma unroll
    for (int r = 0; r < 4; ++r) {
      int m = mb + wave * 16 + (lane >> 4) * 4 + r;
      int co = nb + nt * 16 + fr;
      int b = m >> 11, n = m & (N_ - 1);
      int h = co >> 6, d = co & 63;
      Ov[((size_t)((b * H_ + h) * N_ + n)) * DV_ + d] = f2bf(acc[nt][r]);
    }
  }
}

// ---------------------------------------------------------------------------
// Per-row mask sums: msum[b*N+n] = sum_m masks[b][n][m]
// ---------------------------------------------------------------------------
__global__ __launch_bounds__(256) void msum_kernel(
    const float* __restrict__ masks, float* __restrict__ msum)
{
  const int row = blockIdx.x;
  const int t = threadIdx.x;
  const float* p = masks + (size_t)row * N_;
  float s = 0.f;
#pragma unroll
  for (int i = 0; i < 2; ++i) {
    float4 v = *(const float4*)(p + (size_t)(t + 256 * i) * 4);
    s += v.x + v.y + v.z + v.w;
  }
#pragma unroll
  for (int o = 32; o > 0; o >>= 1) s += __shfl_down(s, o, 64);
  __shared__ float ws4[4];
  if ((t & 63) == 0) ws4[t >> 6] = s;
  __syncthreads();
  if (t == 0) msum[row] = ws4[0] + ws4[1] + ws4[2] + ws4[3];
}

// ---------------------------------------------------------------------------
// Attention: per block = one (b,h,64-row q-tile). No running max needed
// (logits bounded); Z accumulated unmasked, numerator masked.
// ---------------------------------------------------------------------------
__global__ __launch_bounds__(256) void attn_kernel(
    const unsigned short* __restrict__ Qhi, const unsigned short* __restrict__ Qlo,
    const unsigned short* __restrict__ Khi, const unsigned short* __restrict__ Klo,
    const unsigned short* __restrict__ Vh,  const float* __restrict__ masks,
    const float* __restrict__ msum, float* __restrict__ out)
{
  __shared__ __align__(16) unsigned short Ks_h[64][104];
  __shared__ __align__(16) unsigned short Ks_l[64][104];
  __shared__ __align__(16) unsigned short Vt[64][72];   // [d][k] transposed
  __shared__ __align__(16) unsigned short Ps[64][72];   // [qrow][kcol]

  const int qt = blockIdx.x, h = blockIdx.y, b = blockIdx.z;
  const int qbase = qt * 64;
  const int t = threadIdx.x;
  const int wave = t >> 6, lane = t & 63;
  const int fr = lane & 15, kof = (lane >> 4) * 8;

  const size_t bh = (size_t)(b * H_ + h);
  const unsigned short* Qhi_p = Qhi + (bh * N_ + qbase) * DH_;
  const unsigned short* Qlo_p = Qlo + (bh * N_ + qbase) * DH_;
  const unsigned short* Khi_p = Khi + bh * N_ * DH_;
  const unsigned short* Klo_p = Klo + bh * N_ * DH_;
  const unsigned short* Vh_p  = Vh  + bh * N_ * DV_;

  // Q fragments (hi/lo) in registers: rows wave*16+fr, 3 k-steps of 32
  bf16x8 qh8[3], ql8[3];
#pragma unroll
  for (int s = 0; s < 3; ++s) {
    qh8[s] = *(const bf16x8*)(Qhi_p + (size_t)(wave * 16 + fr) * DH_ + s * 32 + kof);
    ql8[s] = *(const bf16x8*)(Qlo_p + (size_t)(wave * 16 + fr) * DH_ + s * 32 + kof);
  }

  f32x4 oacc[4];
#pragma unroll
  for (int i = 0; i < 4; ++i) oacc[i] = (f32x4){0.f, 0.f, 0.f, 0.f};
  float zacc[4] = {0.f, 0.f, 0.f, 0.f};
  const float* mrow[4];
#pragma unroll
  for (int r = 0; r < 4; ++r)
    mrow[r] = masks + ((size_t)b * N_ + qbase + wave * 16 + (lane >> 4) * 4 + r) * N_;

  for (int kb = 0; kb < N_; kb += 64) {
    __syncthreads();
    // stage K hi/lo: 64 rows x 96 = 768 chunks of 8 bf16
#pragma unroll
    for (int i = 0; i < 3; ++i) {
      int c = t + 256 * i;
      int r = c / 12, c8 = (c % 12) * 8;
      *(bf16x8*)&Ks_h[r][c8] = *(const bf16x8*)(Khi_p + (size_t)(kb + r) * DH_ + c8);
      *(bf16x8*)&Ks_l[r][c8] = *(const bf16x8*)(Klo_p + (size_t)(kb + r) * DH_ + c8);
    }
    // stage V transposed: 64 rows x 64 cols -> Vt[d][k]
#pragma unroll
    for (int i = 0; i < 2; ++i) {
      int c = t + 256 * i;
      int r = c >> 3, c8 = (c & 7) * 8;
      bf16x8 v8 = *(const bf16x8*)(Vh_p + (size_t)(kb + r) * DV_ + c8);
#pragma unroll
      for (int j = 0; j < 8; ++j) Vt[c8 + j][r] = (unsigned short)v8[j];
    }
    __syncthreads();

    // S = Q K^T (split: hi*hi + hi*lo + lo*hi)
    f32x4 sacc[4];
#pragma unroll
    for (int i = 0; i < 4; ++i) sacc[i] = (f32x4){0.f, 0.f, 0.f, 0.f};
#pragma unroll
    for (int s = 0; s < 3; ++s) {
#pragma unroll
      for (int nt = 0; nt < 4; ++nt) {
        bf16x8 k_h = *(const bf16x8*)&Ks_h[nt * 16 + fr][s * 32 + kof];
        bf16x8 k_l = *(const bf16x8*)&Ks_l[nt * 16 + fr][s * 32 + kof];
        sacc[nt] = MFMA(qh8[s], k_h, sacc[nt]);
        sacc[nt] = MFMA(qh8[s], k_l, sacc[nt]);
        sacc[nt] = MFMA(ql8[s], k_h, sacc[nt]);
      }
    }

    // P = exp(S*SCALE); Z += P (unmasked); Ps = bf16(P*mask)
#pragma unroll
    for (int nt = 0; nt < 4; ++nt) {
#pragma unroll
      for (int r = 0; r < 4; ++r) {
        float pv = __expf(sacc[nt][r] * SCALE_);
        zacc[r] += pv;
        float mk = mrow[r][kb + nt * 16 + fr];
        Ps[wave * 16 + (lane >> 4) * 4 + r][nt * 16 + fr] = f2bf(pv * mk);
      }
    }
    __syncthreads();

    // O += P V
#pragma unroll
    for (int s2 = 0; s2 < 2; ++s2) {
      bf16x8 pa = *(const bf16x8*)&Ps[wave * 16 + fr][s2 * 32 + kof];
#pragma unroll
      for (int dt = 0; dt < 4; ++dt) {
        bf16x8 vb = *(const bf16x8*)&Vt[dt * 16 + fr][s2 * 32 + kof];
        oacc[dt] = MFMA(pa, vb, oacc[dt]);
      }
    }
  }

  // reduce Z across the 16-lane group holding each row
#pragma unroll
  for (int r = 0; r < 4; ++r) {
    float z = zacc[r];
    z += __shfl_xor(z, 1, 64);
    z += __shfl_xor(z, 2, 64);
    z += __shfl_xor(z, 4, 64);
    z += __shfl_xor(z, 8, 64);
    zacc[r] = z;
  }

#pragma unroll
  for (int dt = 0; dt < 4; ++dt) {
#pragma unroll
    for (int r = 0; r < 4; ++r) {
      int n = qbase + wave * 16 + (lane >> 4) * 4 + r;
      float denom = zacc[r] * 8.f * msum[b * N_ + n];
      out[((size_t)b * N_ + n) * CV_ + h * DV_ + dt * 16 + fr] = oacc[dt][r] / denom;
    }
  }
}

// ---------------------------------------------------------------------------
extern "C" void kernel_launch(void* const* d_in, const int* in_sizes, int n_in,
                              void* d_out, int out_size, void* d_ws, size_t ws_size,
                              hipStream_t stream)
{
  (void)in_sizes; (void)n_in; (void)out_size; (void)ws_size;
  const float* q     = (const float*)d_in[0];
  const float* k     = (const float*)d_in[1];
  const float* v     = (const float*)d_in[2];
  const float* masks = (const float*)d_in[3];
  const float* Wq    = (const float*)d_in[4];
  const float* Wk    = (const float*)d_in[5];
  const float* Wv    = (const float*)d_in[6];
  float* out = (float*)d_out;

  char* ws = (char*)d_ws;
  const size_t qk_elems = (size_t)B_ * H_ * N_ * DH_; // 6,291,456
  const size_t v_elems  = (size_t)B_ * H_ * N_ * DV_; // 4,194,304
  unsigned short* qh_hi = (unsigned short*)ws; ws += qk_elems * 2;
  unsigned short* qh_lo = (unsigned short*)ws; ws += qk_elems * 2;
  unsigned short* kh_hi = (unsigned short*)ws; ws += qk_elems * 2;
  unsigned short* kh_lo = (unsigned short*)ws; ws += qk_elems * 2;
  unsigned short* vh    = (unsigned short*)ws; ws += v_elems * 2;
  float* msumb          = (float*)ws;          ws += (size_t)B_ * N_ * 4;

  proj_split_kernel<<<dim3(128, 12, 1), 256, 0, stream>>>(q, Wq, qh_hi, qh_lo);
  proj_split_kernel<<<dim3(128, 12, 1), 256, 0, stream>>>(k, Wk, kh_hi, kh_lo);
  proj_v_kernel<<<dim3(128, 8, 1), 256, 0, stream>>>(v, Wv, vh);
  msum_kernel<<<dim3(B_ * N_, 1, 1), 256, 0, stream>>>(masks, msumb);
  attn_kernel<<<dim3(N_ / 64, H_, B_), 256, 0, stream>>>(qh_hi, qh_lo, kh_hi, kh_lo,
                                                         vh, masks, msumb, out);
}

// Round 3
// 329.576 us; speedup vs baseline: 1.7835x; 1.7835x over previous
//
#include <hip/hip_runtime.h>

#define B_ 4
#define N_ 2048
#define H_ 8
#define C_ 768
#define CV_ 512
#define DH_ 96
#define DV_ 64
// SCALE = 32^-0.5 = 2^-2.5 ; K2E = SCALE * log2(e) = 0.25503486...
#define K2E_ 0.2550348620270320f

using bf16x8 = __attribute__((ext_vector_type(8))) short;
using f32x4  = __attribute__((ext_vector_type(4))) float;
using u16x4  = __attribute__((ext_vector_type(4))) unsigned short;

__device__ __forceinline__ unsigned short f2bf(float f) {
  union { float f; unsigned u; } x; x.f = f;
  unsigned r = x.u + 0x7fffu + ((x.u >> 16) & 1u);
  return (unsigned short)(r >> 16);
}
__device__ __forceinline__ float bf2f(unsigned short b) {
  union { unsigned u; float f; } x; x.u = ((unsigned)b) << 16;
  return x.f;
}

#define MFMA(a,b,c) __builtin_amdgcn_mfma_f32_16x16x32_bf16((a),(b),(c),0,0,0)

// ---------------------------------------------------------------------------
// Split-precision projection: O = X @ W^T, X:(8192,768), W:(768,768)
// Output stored as bf16 hi+lo at [(b*8+h)*2048+n]*96 + d
// ---------------------------------------------------------------------------
__global__ __launch_bounds__(256) void proj_split_kernel(
    const float* __restrict__ X, const float* __restrict__ W,
    unsigned short* __restrict__ Ohi, unsigned short* __restrict__ Olo)
{
  __shared__ __align__(16) unsigned short Ah[64][72];
  __shared__ __align__(16) unsigned short Al[64][72];
  __shared__ __align__(16) unsigned short Bh[64][72];
  __shared__ __align__(16) unsigned short Bl[64][72];

  const int mb = blockIdx.x * 64;
  const int nb = blockIdx.y * 64;
  const int t = threadIdx.x;
  const int wave = t >> 6;
  const int lane = t & 63;
  const int fr = lane & 15;
  const int kof = (lane >> 4) * 8;

  f32x4 acc[4];
#pragma unroll
  for (int i = 0; i < 4; ++i) acc[i] = (f32x4){0.f, 0.f, 0.f, 0.f};

  for (int kb = 0; kb < C_; kb += 64) {
    __syncthreads();
#pragma unroll
    for (int i = 0; i < 4; ++i) {
      int c = t + 256 * i;
      int r = c >> 4;
      int c4 = (c & 15) * 4;
      float4 xa = *(const float4*)(X + (size_t)(mb + r) * C_ + kb + c4);
      float4 xb = *(const float4*)(W + (size_t)(nb + r) * C_ + kb + c4);
      float va[4] = {xa.x, xa.y, xa.z, xa.w};
      float vb[4] = {xb.x, xb.y, xb.z, xb.w};
      u16x4 ah, al, bh, bl;
#pragma unroll
      for (int j = 0; j < 4; ++j) {
        unsigned short hi = f2bf(va[j]); ah[j] = hi; al[j] = f2bf(va[j] - bf2f(hi));
        unsigned short hj = f2bf(vb[j]); bh[j] = hj; bl[j] = f2bf(vb[j] - bf2f(hj));
      }
      *(u16x4*)&Ah[r][c4] = ah; *(u16x4*)&Al[r][c4] = al;
      *(u16x4*)&Bh[r][c4] = bh; *(u16x4*)&Bl[r][c4] = bl;
    }
    __syncthreads();
#pragma unroll
    for (int s = 0; s < 2; ++s) {
      bf16x8 a_h = *(const bf16x8*)&Ah[wave * 16 + fr][s * 32 + kof];
      bf16x8 a_l = *(const bf16x8*)&Al[wave * 16 + fr][s * 32 + kof];
#pragma unroll
      for (int nt = 0; nt < 4; ++nt) {
        bf16x8 b_h = *(const bf16x8*)&Bh[nt * 16 + fr][s * 32 + kof];
        bf16x8 b_l = *(const bf16x8*)&Bl[nt * 16 + fr][s * 32 + kof];
        acc[nt] = MFMA(a_h, b_h, acc[nt]);
        acc[nt] = MFMA(a_h, b_l, acc[nt]);
        acc[nt] = MFMA(a_l, b_h, acc[nt]);
      }
    }
  }
#pragma unroll
  for (int nt = 0; nt < 4; ++nt) {
#pragma unroll
    for (int r = 0; r < 4; ++r) {
      int m = mb + wave * 16 + (lane >> 4) * 4 + r;
      int co = nb + nt * 16 + fr;
      int b = m >> 11, n = m & (N_ - 1);
      int h = co / DH_, d = co % DH_;
      size_t idx = ((size_t)((b * H_ + h) * N_ + n)) * DH_ + d;
      float vv = acc[nt][r];
      unsigned short hi = f2bf(vv);
      Ohi[idx] = hi;
      Olo[idx] = f2bf(vv - bf2f(hi));
    }
  }
}

// ---------------------------------------------------------------------------
// V projection storing V^T: OvT[(b*8+h)*64 + d][n] (bf16)
// ---------------------------------------------------------------------------
__global__ __launch_bounds__(256) void proj_v_kernel(
    const float* __restrict__ X, const float* __restrict__ W,
    unsigned short* __restrict__ OvT)
{
  __shared__ __align__(16) unsigned short As[64][72];
  __shared__ __align__(16) unsigned short Bs[64][72];

  const int mb = blockIdx.x * 64;
  const int nb = blockIdx.y * 64;
  const int t = threadIdx.x;
  const int wave = t >> 6;
  const int lane = t & 63;
  const int fr = lane & 15;
  const int kof = (lane >> 4) * 8;

  f32x4 acc[4];
#pragma unroll
  for (int i = 0; i < 4; ++i) acc[i] = (f32x4){0.f, 0.f, 0.f, 0.f};

  for (int kb = 0; kb < CV_; kb += 64) {
    __syncthreads();
#pragma unroll
    for (int i = 0; i < 4; ++i) {
      int c = t + 256 * i;
      int r = c >> 4;
      int c4 = (c & 15) * 4;
      float4 xa = *(const float4*)(X + (size_t)(mb + r) * CV_ + kb + c4);
      float4 xb = *(const float4*)(W + (size_t)(nb + r) * CV_ + kb + c4);
      u16x4 ah, bh;
      ah[0] = f2bf(xa.x); ah[1] = f2bf(xa.y); ah[2] = f2bf(xa.z); ah[3] = f2bf(xa.w);
      bh[0] = f2bf(xb.x); bh[1] = f2bf(xb.y); bh[2] = f2bf(xb.z); bh[3] = f2bf(xb.w);
      *(u16x4*)&As[r][c4] = ah;
      *(u16x4*)&Bs[r][c4] = bh;
    }
    __syncthreads();
#pragma unroll
    for (int s = 0; s < 2; ++s) {
      bf16x8 a8 = *(const bf16x8*)&As[wave * 16 + fr][s * 32 + kof];
#pragma unroll
      for (int nt = 0; nt < 4; ++nt) {
        bf16x8 b8 = *(const bf16x8*)&Bs[nt * 16 + fr][s * 32 + kof];
        acc[nt] = MFMA(a8, b8, acc[nt]);
      }
    }
  }
  // store V^T: 4 consecutive n per lane -> one b64 store
#pragma unroll
  for (int nt = 0; nt < 4; ++nt) {
    int co = nb + nt * 16 + fr;
    int h = co >> 6, d = co & 63;
    int m = mb + wave * 16 + (lane >> 4) * 4;
    int b = m >> 11, n = m & (N_ - 1);
    u16x4 pk;
#pragma unroll
    for (int r = 0; r < 4; ++r) pk[r] = f2bf(acc[nt][r]);
    *(u16x4*)(OvT + ((size_t)((b * H_ + h) * DV_ + d)) * N_ + n) = pk;
  }
}

// ---------------------------------------------------------------------------
// Mask pre-pass: bf16 copy + per-row sum. One block per (b,n) row.
// ---------------------------------------------------------------------------
__global__ __launch_bounds__(256) void mask_prep_kernel(
    const float* __restrict__ masks, unsigned short* __restrict__ mask_bf,
    float* __restrict__ msum)
{
  const int row = blockIdx.x;
  const int t = threadIdx.x;
  const float* p = masks + (size_t)row * N_;
  unsigned short* o = mask_bf + (size_t)row * N_;
  float4 v0 = *(const float4*)(p + t * 8);
  float4 v1 = *(const float4*)(p + t * 8 + 4);
  float s = v0.x + v0.y + v0.z + v0.w + v1.x + v1.y + v1.z + v1.w;
  u16x4 a, b;
  a[0] = f2bf(v0.x); a[1] = f2bf(v0.y); a[2] = f2bf(v0.z); a[3] = f2bf(v0.w);
  b[0] = f2bf(v1.x); b[1] = f2bf(v1.y); b[2] = f2bf(v1.z); b[3] = f2bf(v1.w);
  *(u16x4*)(o + t * 8) = a;
  *(u16x4*)(o + t * 8 + 4) = b;
#pragma unroll
  for (int ofs = 32; ofs > 0; ofs >>= 1) s += __shfl_down(s, ofs, 64);
  __shared__ float ws4[4];
  if ((t & 63) == 0) ws4[t >> 6] = s;
  __syncthreads();
  if (t == 0) msum[row] = ws4[0] + ws4[1] + ws4[2] + ws4[3];
}

// ---------------------------------------------------------------------------
// Attention: block = (b, h, 128-row q-tile); 4 waves x 32 q-rows.
// S^T = MFMA(K, Q): lane holds q=fr, consecutive k -> vector mask loads &
// vector Ps writes. V^T staged coalesced. Reg prefetch of next K/V tile.
// ---------------------------------------------------------------------------
__global__ __launch_bounds__(256, 2) void attn_kernel(
    const unsigned short* __restrict__ Qhi, const unsigned short* __restrict__ Qlo,
    const unsigned short* __restrict__ Khi, const unsigned short* __restrict__ Klo,
    const unsigned short* __restrict__ VT,  const unsigned short* __restrict__ mask_bf,
    const float* __restrict__ msum, float* __restrict__ out)
{
  __shared__ __align__(16) unsigned short Ks_h[64][104];
  __shared__ __align__(16) unsigned short Ks_l[64][104];
  __shared__ __align__(16) unsigned short Vs[64][72];    // V^T tile: [d][k]
  __shared__ __align__(16) unsigned short Ps[128][72];   // P: [q][k_local]

  const int qbase = blockIdx.x * 128;
  const int h = blockIdx.y, b = blockIdx.z;
  const int t = threadIdx.x;
  const int w = t >> 6, lane = t & 63;
  const int fr = lane & 15, g = lane >> 4;
  const int kof = g * 8;

  const size_t bh = (size_t)(b * H_ + h);
  const unsigned short* Khi_p = Khi + bh * N_ * DH_;
  const unsigned short* Klo_p = Klo + bh * N_ * DH_;
  const unsigned short* VT_p  = VT  + bh * DV_ * N_;

  // Q fragments (B-operand): 2 q-groups per wave
  bf16x8 qh[2][3], ql[2][3];
  size_t mrow_base[2];
  int qrow[2];
#pragma unroll
  for (int wq = 0; wq < 2; ++wq) {
    qrow[wq] = qbase + w * 32 + wq * 16 + fr;
    mrow_base[wq] = ((size_t)b * N_ + qrow[wq]) * N_;
#pragma unroll
    for (int s = 0; s < 3; ++s) {
      qh[wq][s] = *(const bf16x8*)(Qhi + (bh * N_ + qrow[wq]) * DH_ + s * 32 + kof);
      ql[wq][s] = *(const bf16x8*)(Qlo + (bh * N_ + qrow[wq]) * DH_ + s * 32 + kof);
    }
  }

  // prefetch registers for K(hi,lo) + V^T tile
  bf16x8 pk[6], pvv[2];
  int krow[3], kcol[3], vrow[2], vcol[2];
#pragma unroll
  for (int i = 0; i < 3; ++i) { int c = t + 256 * i; krow[i] = c / 12; kcol[i] = (c % 12) * 8; }
#pragma unroll
  for (int i = 0; i < 2; ++i) { int c = t + 256 * i; vrow[i] = c >> 3; vcol[i] = (c & 7) * 8; }

  auto load_regs = [&](int kb) {
#pragma unroll
    for (int i = 0; i < 3; ++i) {
      pk[i]     = *(const bf16x8*)(Khi_p + (size_t)(kb + krow[i]) * DH_ + kcol[i]);
      pk[3 + i] = *(const bf16x8*)(Klo_p + (size_t)(kb + krow[i]) * DH_ + kcol[i]);
    }
#pragma unroll
    for (int i = 0; i < 2; ++i)
      pvv[i] = *(const bf16x8*)(VT_p + (size_t)vrow[i] * N_ + kb + vcol[i]);
  };

  f32x4 oacc[2][4];
#pragma unroll
  for (int wq = 0; wq < 2; ++wq)
#pragma unroll
    for (int i = 0; i < 4; ++i) oacc[wq][i] = (f32x4){0.f, 0.f, 0.f, 0.f};
  float z[2] = {0.f, 0.f};

  load_regs(0);

  for (int kt = 0; kt < N_ / 64; ++kt) {
    const int kb = kt * 64;
    __syncthreads();
#pragma unroll
    for (int i = 0; i < 3; ++i) {
      *(bf16x8*)&Ks_h[krow[i]][kcol[i]] = pk[i];
      *(bf16x8*)&Ks_l[krow[i]][kcol[i]] = pk[3 + i];
    }
#pragma unroll
    for (int i = 0; i < 2; ++i) *(bf16x8*)&Vs[vrow[i]][vcol[i]] = pvv[i];
    __syncthreads();

    if (kt + 1 < N_ / 64) load_regs(kb + 64);

    // mask loads early (b64 bf16x4), consumed after QK
    u16x4 mk[2][4];
#pragma unroll
    for (int wq = 0; wq < 2; ++wq)
#pragma unroll
      for (int a = 0; a < 4; ++a)
        mk[wq][a] = *(const u16x4*)(mask_bf + mrow_base[wq] + kb + a * 16 + g * 4);

    // S^T = K * Q^T: lane holds q=fr, k rows a*16+g*4+r
    f32x4 sacc[2][4];
#pragma unroll
    for (int wq = 0; wq < 2; ++wq)
#pragma unroll
      for (int a = 0; a < 4; ++a) sacc[wq][a] = (f32x4){0.f, 0.f, 0.f, 0.f};
#pragma unroll
    for (int s = 0; s < 3; ++s) {
#pragma unroll
      for (int a = 0; a < 4; ++a) {
        bf16x8 kh = *(const bf16x8*)&Ks_h[a * 16 + fr][s * 32 + kof];
        bf16x8 kl = *(const bf16x8*)&Ks_l[a * 16 + fr][s * 32 + kof];
#pragma unroll
        for (int wq = 0; wq < 2; ++wq) {
          sacc[wq][a] = MFMA(kh, qh[wq][s], sacc[wq][a]);
          sacc[wq][a] = MFMA(kh, ql[wq][s], sacc[wq][a]);
          sacc[wq][a] = MFMA(kl, qh[wq][s], sacc[wq][a]);
        }
      }
    }

    // softmax numerator: P = exp2(S*K2E); Z += P; Ps = bf16(P*mask)
#pragma unroll
    for (int wq = 0; wq < 2; ++wq) {
#pragma unroll
      for (int a = 0; a < 4; ++a) {
        u16x4 pb;
#pragma unroll
        for (int r = 0; r < 4; ++r) {
          float e = exp2f(sacc[wq][a][r] * K2E_);
          z[wq] += e;
          pb[r] = f2bf(e * bf2f(mk[wq][a][r]));
        }
        *(u16x4*)&Ps[w * 32 + wq * 16 + fr][a * 16 + g * 4] = pb;
      }
    }

    // O += P V  (Ps rows are wave-private: no barrier needed)
#pragma unroll
    for (int s2 = 0; s2 < 2; ++s2) {
      bf16x8 pa[2];
#pragma unroll
      for (int wq = 0; wq < 2; ++wq)
        pa[wq] = *(const bf16x8*)&Ps[w * 32 + wq * 16 + fr][s2 * 32 + kof];
#pragma unroll
      for (int dt = 0; dt < 4; ++dt) {
        bf16x8 vb = *(const bf16x8*)&Vs[dt * 16 + fr][s2 * 32 + kof];
#pragma unroll
        for (int wq = 0; wq < 2; ++wq)
          oacc[wq][dt] = MFMA(pa[wq], vb, oacc[wq][dt]);
      }
    }
  }

  // Z: reduce across the 4 k-row groups (lanes fr, fr+16, fr+32, fr+48)
#pragma unroll
  for (int wq = 0; wq < 2; ++wq) {
    z[wq] += __shfl_xor(z[wq], 16, 64);
    z[wq] += __shfl_xor(z[wq], 32, 64);
  }

  // epilogue: output rows are q16 = g*4+r; Z lives at lane fr=q16
#pragma unroll
  for (int wq = 0; wq < 2; ++wq) {
#pragma unroll
    for (int r = 0; r < 4; ++r) {
      int q = qbase + w * 32 + wq * 16 + g * 4 + r;
      float Z = __shfl(z[wq], g * 4 + r, 64);
      float inv = 1.0f / (Z * 8.0f * msum[b * N_ + q]);
#pragma unroll
      for (int dt = 0; dt < 4; ++dt)
        out[((size_t)b * N_ + q) * CV_ + h * DV_ + dt * 16 + fr] = oacc[wq][dt][r] * inv;
    }
  }
}

// ---------------------------------------------------------------------------
extern "C" void kernel_launch(void* const* d_in, const int* in_sizes, int n_in,
                              void* d_out, int out_size, void* d_ws, size_t ws_size,
                              hipStream_t stream)
{
  (void)in_sizes; (void)n_in; (void)out_size; (void)ws_size;
  const float* q     = (const float*)d_in[0];
  const float* k     = (const float*)d_in[1];
  const float* v     = (const float*)d_in[2];
  const float* masks = (const float*)d_in[3];
  const float* Wq    = (const float*)d_in[4];
  const float* Wk    = (const float*)d_in[5];
  const float* Wv    = (const float*)d_in[6];
  float* out = (float*)d_out;

  char* ws = (char*)d_ws;
  const size_t qk_elems = (size_t)B_ * H_ * N_ * DH_; // 6,291,456
  const size_t v_elems  = (size_t)B_ * H_ * N_ * DV_; // 4,194,304
  const size_t m_elems  = (size_t)B_ * N_ * N_;       // 16,777,216
  unsigned short* qh_hi = (unsigned short*)ws; ws += qk_elems * 2;
  unsigned short* qh_lo = (unsigned short*)ws; ws += qk_elems * 2;
  unsigned short* kh_hi = (unsigned short*)ws; ws += qk_elems * 2;
  unsigned short* kh_lo = (unsigned short*)ws; ws += qk_elems * 2;
  unsigned short* vT    = (unsigned short*)ws; ws += v_elems * 2;
  unsigned short* mbf   = (unsigned short*)ws; ws += m_elems * 2;
  float* msumb          = (float*)ws;          ws += (size_t)B_ * N_ * 4;

  proj_split_kernel<<<dim3(128, 12, 1), 256, 0, stream>>>(q, Wq, qh_hi, qh_lo);
  proj_split_kernel<<<dim3(128, 12, 1), 256, 0, stream>>>(k, Wk, kh_hi, kh_lo);
  proj_v_kernel<<<dim3(128, 8, 1), 256, 0, stream>>>(v, Wv, vT);
  mask_prep_kernel<<<dim3(B_ * N_, 1, 1), 256, 0, stream>>>(masks, mbf, msumb);
  attn_kernel<<<dim3(N_ / 128, H_, B_), 256, 0, stream>>>(qh_hi, qh_lo, kh_hi, kh_lo,
                                                          vT, mbf, msumb, out);
}

// Round 5
// 280.076 us; speedup vs baseline: 2.0987x; 1.1767x over previous
//
#include <hip/hip_runtime.h>

#define B_ 4
#define N_ 2048
#define H_ 8
#define C_ 768
#define CV_ 512
#define DH_ 96
#define DV_ 64
// SCALE = 32^-0.5 = 2^-2.5 ; K2E = SCALE * log2(e) = 0.25503486...
#define K2E_ 0.2550348620270320f

using bf16x8 = __attribute__((ext_vector_type(8))) short;
using f32x4  = __attribute__((ext_vector_type(4))) float;
using u16x4  = __attribute__((ext_vector_type(4))) unsigned short;

__device__ __forceinline__ unsigned short f2bf(float f) {
  union { float f; unsigned u; } x; x.f = f;
  unsigned r = x.u + 0x7fffu + ((x.u >> 16) & 1u);
  return (unsigned short)(r >> 16);
}
__device__ __forceinline__ float bf2f(unsigned short b) {
  union { unsigned u; float f; } x; x.u = ((unsigned)b) << 16;
  return x.f;
}
__device__ __forceinline__ void gload16(const void* g, void* l) {
  __builtin_amdgcn_global_load_lds(
      (const __attribute__((address_space(1))) void*)g,
      (__attribute__((address_space(3))) void*)l, 16, 0, 0);
}

#define MFMA(a,b,c) __builtin_amdgcn_mfma_f32_16x16x32_bf16((a),(b),(c),0,0,0)

// ---------------------------------------------------------------------------
// f32 -> bf16 hi/lo split conversion. 8 elems/thread, exact-size grid.
// ---------------------------------------------------------------------------
__global__ __launch_bounds__(256) void convert_kernel(
    const float* __restrict__ in, unsigned short* __restrict__ hi,
    unsigned short* __restrict__ lo)
{
  const size_t i8 = ((size_t)blockIdx.x * 256 + threadIdx.x) * 8;
  float4 v0 = *(const float4*)(in + i8);
  float4 v1 = *(const float4*)(in + i8 + 4);
  float v[8] = {v0.x, v0.y, v0.z, v0.w, v1.x, v1.y, v1.z, v1.w};
  u16x4 h0, h1, l0, l1;
#pragma unroll
  for (int j = 0; j < 4; ++j) {
    unsigned short hb = f2bf(v[j]);     h0[j] = hb; l0[j] = f2bf(v[j] - bf2f(hb));
    unsigned short hc = f2bf(v[j + 4]); h1[j] = hc; l1[j] = f2bf(v[j + 4] - bf2f(hc));
  }
  *(u16x4*)(hi + i8) = h0; *(u16x4*)(hi + i8 + 4) = h1;
  *(u16x4*)(lo + i8) = l0; *(u16x4*)(lo + i8 + 4) = l1;
}

// ---------------------------------------------------------------------------
// Split GEMM: O = scale * (X @ W^T), X:(8192,768) hi/lo bf16, W:(768,768).
// 128x128 tile, BK=64, global_load_lds(16B), LINEAR LDS (m97 structure).
// Output: bf16 hi+lo at [(b*8+h)*2048+n]*96+d.
// ---------------------------------------------------------------------------
__global__ __launch_bounds__(256) void proj_qk_kernel(
    const unsigned short* __restrict__ Xhi, const unsigned short* __restrict__ Xlo,
    const unsigned short* __restrict__ Whi, const unsigned short* __restrict__ Wlo,
    unsigned short* __restrict__ Ohi, unsigned short* __restrict__ Olo, float scale)
{
  __shared__ __align__(16) unsigned short Ah[128 * 64];
  __shared__ __align__(16) unsigned short Al[128 * 64];
  __shared__ __align__(16) unsigned short Bh[128 * 64];
  __shared__ __align__(16) unsigned short Bl[128 * 64];

  const int mb = blockIdx.x * 128, nb = blockIdx.y * 128;
  const int t = threadIdx.x, w = t >> 6, lane = t & 63;
  const int fr = lane & 15, g = lane >> 4;
  const int wr = w >> 1, wc = w & 1;

  // staging: 16 issues of 1024B per 16KB tile; wave w covers issues w*4..w*4+3.
  // LDS linear: LDS[r][c] = X[row_base + r][kb + c], row stride 64 elems.
  int offA[4], offB[4];
  unsigned ldsB[4];
#pragma unroll
  for (int j = 0; j < 4; ++j) {
    int lin = ((w * 4 + j) << 10) + (lane << 4);
    int r = lin >> 7, ce = (lin & 127) >> 1;
    offA[j] = (mb + r) * C_ + ce;
    offB[j] = (nb + r) * C_ + ce;
    ldsB[j] = (unsigned)((w * 4 + j) << 10);
  }

  f32x4 acc[4][4];
#pragma unroll
  for (int m = 0; m < 4; ++m)
#pragma unroll
    for (int n = 0; n < 4; ++n) acc[m][n] = (f32x4){0.f, 0.f, 0.f, 0.f};

  for (int kt = 0; kt < C_ / 64; ++kt) {
    const int kb = kt * 64;
    __syncthreads();
#pragma unroll
    for (int j = 0; j < 4; ++j) {
      gload16(Xhi + offA[j] + kb, (char*)Ah + ldsB[j]);
      gload16(Xlo + offA[j] + kb, (char*)Al + ldsB[j]);
      gload16(Whi + offB[j] + kb, (char*)Bh + ldsB[j]);
      gload16(Wlo + offB[j] + kb, (char*)Bl + ldsB[j]);
    }
    __syncthreads();
#pragma unroll
    for (int s = 0; s < 2; ++s) {
      const int cbyte = s * 64 + g * 16;
      bf16x8 ah[4], al[4], bh2[4], bl2[4];
#pragma unroll
      for (int m = 0; m < 4; ++m) {
        int ab = (wr * 64 + m * 16 + fr) * 128 + cbyte;
        ah[m] = *(const bf16x8*)((const char*)Ah + ab);
        al[m] = *(const bf16x8*)((const char*)Al + ab);
      }
#pragma unroll
      for (int n = 0; n < 4; ++n) {
        int bb = (wc * 64 + n * 16 + fr) * 128 + cbyte;
        bh2[n] = *(const bf16x8*)((const char*)Bh + bb);
        bl2[n] = *(const bf16x8*)((const char*)Bl + bb);
      }
#pragma unroll
      for (int m = 0; m < 4; ++m)
#pragma unroll
        for (int n = 0; n < 4; ++n) {
          acc[m][n] = MFMA(ah[m], bh2[n], acc[m][n]);
          acc[m][n] = MFMA(ah[m], bl2[n], acc[m][n]);
          acc[m][n] = MFMA(al[m], bh2[n], acc[m][n]);
        }
    }
  }

#pragma unroll
  for (int m = 0; m < 4; ++m) {
    const int Mrow = mb + wr * 64 + m * 16 + g * 4;
#pragma unroll
    for (int n = 0; n < 4; ++n) {
      const int co = nb + wc * 64 + n * 16 + fr;
      const int h = co / DH_, d = co - h * DH_;
#pragma unroll
      for (int r = 0; r < 4; ++r) {
        const int M = Mrow + r;
        const int b = M >> 11, nn = M & (N_ - 1);
        size_t idx = ((size_t)((b * H_ + h) * N_ + nn)) * DH_ + d;
        float vv = acc[m][n][r] * scale;
        unsigned short hb = f2bf(vv);
        Ohi[idx] = hb;
        Olo[idx] = f2bf(vv - bf2f(hb));
      }
    }
  }
}

// ---------------------------------------------------------------------------
// V projection storing V^T: OvT[(b*8+h)*64 + d][n] (bf16)
// ---------------------------------------------------------------------------
__global__ __launch_bounds__(256) void proj_v_kernel(
    const float* __restrict__ X, const float* __restrict__ W,
    unsigned short* __restrict__ OvT)
{
  __shared__ __align__(16) unsigned short As[64][72];
  __shared__ __align__(16) unsigned short Bs[64][72];

  const int mb = blockIdx.x * 64;
  const int nb = blockIdx.y * 64;
  const int t = threadIdx.x;
  const int wave = t >> 6;
  const int lane = t & 63;
  const int fr = lane & 15;
  const int kof = (lane >> 4) * 8;

  f32x4 acc[4];
#pragma unroll
  for (int i = 0; i < 4; ++i) acc[i] = (f32x4){0.f, 0.f, 0.f, 0.f};

  for (int kb = 0; kb < CV_; kb += 64) {
    __syncthreads();
#pragma unroll
    for (int i = 0; i < 4; ++i) {
      int c = t + 256 * i;
      int r = c >> 4;
      int c4 = (c & 15) * 4;
      float4 xa = *(const float4*)(X + (size_t)(mb + r) * CV_ + kb + c4);
      float4 xb = *(const float4*)(W + (size_t)(nb + r) * CV_ + kb + c4);
      u16x4 ah, bh;
      ah[0] = f2bf(xa.x); ah[1] = f2bf(xa.y); ah[2] = f2bf(xa.z); ah[3] = f2bf(xa.w);
      bh[0] = f2bf(xb.x); bh[1] = f2bf(xb.y); bh[2] = f2bf(xb.z); bh[3] = f2bf(xb.w);
      *(u16x4*)&As[r][c4] = ah;
      *(u16x4*)&Bs[r][c4] = bh;
    }
    __syncthreads();
#pragma unroll
    for (int s = 0; s < 2; ++s) {
      bf16x8 a8 = *(const bf16x8*)&As[wave * 16 + fr][s * 32 + kof];
#pragma unroll
      for (int nt = 0; nt < 4; ++nt) {
        bf16x8 b8 = *(const bf16x8*)&Bs[nt * 16 + fr][s * 32 + kof];
        acc[nt] = MFMA(a8, b8, acc[nt]);
      }
    }
  }
#pragma unroll
  for (int nt = 0; nt < 4; ++nt) {
    int co = nb + nt * 16 + fr;
    int h = co >> 6, d = co & 63;
    int m = mb + wave * 16 + (lane >> 4) * 4;
    int b = m >> 11, n = m & (N_ - 1);
    u16x4 pk;
#pragma unroll
    for (int r = 0; r < 4; ++r) pk[r] = f2bf(acc[nt][r]);
    *(u16x4*)(OvT + ((size_t)((b * H_ + h) * DV_ + d)) * N_ + n) = pk;
  }
}

// ---------------------------------------------------------------------------
// Per-row mask sums: msum[b*N+n] = sum_m masks[b][n][m]
// ---------------------------------------------------------------------------
__global__ __launch_bounds__(256) void msum_kernel(
    const float* __restrict__ masks, float* __restrict__ msum)
{
  const int row = blockIdx.x;
  const int t = threadIdx.x;
  const float* p = masks + (size_t)row * N_;
  float4 v0 = *(const float4*)(p + t * 8);
  float4 v1 = *(const float4*)(p + t * 8 + 4);
  float s = v0.x + v0.y + v0.z + v0.w + v1.x + v1.y + v1.z + v1.w;
#pragma unroll
  for (int o = 32; o > 0; o >>= 1) s += __shfl_down(s, o, 64);
  __shared__ float ws4[4];
  if ((t & 63) == 0) ws4[t >> 6] = s;
  __syncthreads();
  if (t == 0) msum[row] = ws4[0] + ws4[1] + ws4[2] + ws4[3];
}

// ---------------------------------------------------------------------------
// Attention: block = (h, qtile, b); 4 waves x 32 q-rows. Q pre-scaled by
// K2E so P = exp2(S). f32 mask float4 loads.
// ---------------------------------------------------------------------------
__global__ __launch_bounds__(256, 2) void attn_kernel(
    const unsigned short* __restrict__ Qhi, const unsigned short* __restrict__ Qlo,
    const unsigned short* __restrict__ Khi, const unsigned short* __restrict__ Klo,
    const unsigned short* __restrict__ VT,  const float* __restrict__ masks,
    const float* __restrict__ msum, float* __restrict__ out)
{
  __shared__ __align__(16) unsigned short Ks_h[64][104];
  __shared__ __align__(16) unsigned short Ks_l[64][104];
  __shared__ __align__(16) unsigned short Vs[64][72];    // V^T tile: [d][k]
  __shared__ __align__(16) unsigned short Ps[128][72];   // P: [q][k_local]

  const int h = blockIdx.x;
  const int qbase = blockIdx.y * 128;
  const int b = blockIdx.z;
  const int t = threadIdx.x;
  const int w = t >> 6, lane = t & 63;
  const int fr = lane & 15, g = lane >> 4;
  const int kof = g * 8;

  const size_t bh = (size_t)(b * H_ + h);
  const unsigned short* Khi_p = Khi + bh * N_ * DH_;
  const unsigned short* Klo_p = Klo + bh * N_ * DH_;
  const unsigned short* VT_p  = VT  + bh * DV_ * N_;

  bf16x8 qh[2][3], ql[2][3];
  size_t mrow_base[2];
#pragma unroll
  for (int wq = 0; wq < 2; ++wq) {
    int qrow = qbase + w * 32 + wq * 16 + fr;
    mrow_base[wq] = ((size_t)b * N_ + qrow) * N_;
#pragma unroll
    for (int s = 0; s < 3; ++s) {
      qh[wq][s] = *(const bf16x8*)(Qhi + (bh * N_ + qrow) * DH_ + s * 32 + kof);
      ql[wq][s] = *(const bf16x8*)(Qlo + (bh * N_ + qrow) * DH_ + s * 32 + kof);
    }
  }

  bf16x8 pk[6], pvv[2];
  int krow[3], kcol[3], vrow[2], vcol[2];
#pragma unroll
  for (int i = 0; i < 3; ++i) { int c = t + 256 * i; krow[i] = c / 12; kcol[i] = (c % 12) * 8; }
#pragma unroll
  for (int i = 0; i < 2; ++i) { int c = t + 256 * i; vrow[i] = c >> 3; vcol[i] = (c & 7) * 8; }

  auto load_regs = [&](int kb) {
#pragma unroll
    for (int i = 0; i < 3; ++i) {
      pk[i]     = *(const bf16x8*)(Khi_p + (size_t)(kb + krow[i]) * DH_ + kcol[i]);
      pk[3 + i] = *(const bf16x8*)(Klo_p + (size_t)(kb + krow[i]) * DH_ + kcol[i]);
    }
#pragma unroll
    for (int i = 0; i < 2; ++i)
      pvv[i] = *(const bf16x8*)(VT_p + (size_t)vrow[i] * N_ + kb + vcol[i]);
  };

  f32x4 oacc[2][4];
#pragma unroll
  for (int wq = 0; wq < 2; ++wq)
#pragma unroll
    for (int i = 0; i < 4; ++i) oacc[wq][i] = (f32x4){0.f, 0.f, 0.f, 0.f};
  float z[2] = {0.f, 0.f};

  load_regs(0);

  for (int kt = 0; kt < N_ / 64; ++kt) {
    const int kb = kt * 64;
    __syncthreads();
#pragma unroll
    for (int i = 0; i < 3; ++i) {
      *(bf16x8*)&Ks_h[krow[i]][kcol[i]] = pk[i];
      *(bf16x8*)&Ks_l[krow[i]][kcol[i]] = pk[3 + i];
    }
#pragma unroll
    for (int i = 0; i < 2; ++i) *(bf16x8*)&Vs[vrow[i]][vcol[i]] = pvv[i];
    __syncthreads();

    if (kt + 1 < N_ / 64) load_regs(kb + 64);

    float4 mk4[2][4];
#pragma unroll
    for (int wq = 0; wq < 2; ++wq)
#pragma unroll
      for (int a = 0; a < 4; ++a)
        mk4[wq][a] = *(const float4*)(masks + mrow_base[wq] + kb + a * 16 + g * 4);

    f32x4 sacc[2][4];
#pragma unroll
    for (int wq = 0; wq < 2; ++wq)
#pragma unroll
      for (int a = 0; a < 4; ++a) sacc[wq][a] = (f32x4){0.f, 0.f, 0.f, 0.f};
#pragma unroll
    for (int s = 0; s < 3; ++s) {
#pragma unroll
      for (int a = 0; a < 4; ++a) {
        bf16x8 kh = *(const bf16x8*)&Ks_h[a * 16 + fr][s * 32 + kof];
        bf16x8 kl = *(const bf16x8*)&Ks_l[a * 16 + fr][s * 32 + kof];
#pragma unroll
        for (int wq = 0; wq < 2; ++wq) {
          sacc[wq][a] = MFMA(kh, qh[wq][s], sacc[wq][a]);
          sacc[wq][a] = MFMA(kh, ql[wq][s], sacc[wq][a]);
          sacc[wq][a] = MFMA(kl, qh[wq][s], sacc[wq][a]);
        }
      }
    }

    // P = exp2(S) (Q pre-scaled); Z += P; Ps = bf16(P*mask)
#pragma unroll
    for (int wq = 0; wq < 2; ++wq) {
#pragma unroll
      for (int a = 0; a < 4; ++a) {
        u16x4 pb;
#pragma unroll
        for (int r = 0; r < 4; ++r) {
          float e = exp2f(sacc[wq][a][r]);
          z[wq] += e;
          float mkv = (r == 0) ? mk4[wq][a].x : (r == 1) ? mk4[wq][a].y
                    : (r == 2) ? mk4[wq][a].z : mk4[wq][a].w;
          pb[r] = f2bf(e * mkv);
        }
        *(u16x4*)&Ps[w * 32 + wq * 16 + fr][a * 16 + g * 4] = pb;
      }
    }

    // O += P V  (Ps rows wave-private)
#pragma unroll
    for (int s2 = 0; s2 < 2; ++s2) {
      bf16x8 pa[2];
#pragma unroll
      for (int wq = 0; wq < 2; ++wq)
        pa[wq] = *(const bf16x8*)&Ps[w * 32 + wq * 16 + fr][s2 * 32 + kof];
#pragma unroll
      for (int dt = 0; dt < 4; ++dt) {
        bf16x8 vb = *(const bf16x8*)&Vs[dt * 16 + fr][s2 * 32 + kof];
#pragma unroll
        for (int wq = 0; wq < 2; ++wq)
          oacc[wq][dt] = MFMA(pa[wq], vb, oacc[wq][dt]);
      }
    }
  }

#pragma unroll
  for (int wq = 0; wq < 2; ++wq) {
    z[wq] += __shfl_xor(z[wq], 16, 64);
    z[wq] += __shfl_xor(z[wq], 32, 64);
  }

#pragma unroll
  for (int wq = 0; wq < 2; ++wq) {
#pragma unroll
    for (int r = 0; r < 4; ++r) {
      int q = qbase + w * 32 + wq * 16 + g * 4 + r;
      float Z = __shfl(z[wq], g * 4 + r, 64);
      float inv = 1.0f / (Z * 8.0f * msum[b * N_ + q]);
#pragma unroll
      for (int dt = 0; dt < 4; ++dt)
        out[((size_t)b * N_ + q) * CV_ + h * DV_ + dt * 16 + fr] = oacc[wq][dt][r] * inv;
    }
  }
}

// ---------------------------------------------------------------------------
extern "C" void kernel_launch(void* const* d_in, const int* in_sizes, int n_in,
                              void* d_out, int out_size, void* d_ws, size_t ws_size,
                              hipStream_t stream)
{
  (void)in_sizes; (void)n_in; (void)out_size; (void)ws_size;
  const float* q     = (const float*)d_in[0];
  const float* k     = (const float*)d_in[1];
  const float* v     = (const float*)d_in[2];
  const float* masks = (const float*)d_in[3];
  const float* Wq    = (const float*)d_in[4];
  const float* Wk    = (const float*)d_in[5];
  const float* Wv    = (const float*)d_in[6];
  float* out = (float*)d_out;

  char* ws = (char*)d_ws;
  const size_t qk_elems = (size_t)B_ * N_ * C_;       // 6,291,456
  const size_t w_elems  = (size_t)C_ * C_;            // 589,824
  const size_t v_elems  = (size_t)B_ * H_ * N_ * DV_; // 4,194,304
  unsigned short* Xhi   = (unsigned short*)ws; ws += qk_elems * 2;
  unsigned short* Xlo   = (unsigned short*)ws; ws += qk_elems * 2;
  unsigned short* Wqhi  = (unsigned short*)ws; ws += w_elems * 2;
  unsigned short* Wqlo  = (unsigned short*)ws; ws += w_elems * 2;
  unsigned short* Wkhi  = (unsigned short*)ws; ws += w_elems * 2;
  unsigned short* Wklo  = (unsigned short*)ws; ws += w_elems * 2;
  unsigned short* qh_hi = (unsigned short*)ws; ws += qk_elems * 2;
  unsigned short* qh_lo = (unsigned short*)ws; ws += qk_elems * 2;
  unsigned short* kh_hi = (unsigned short*)ws; ws += qk_elems * 2;
  unsigned short* kh_lo = (unsigned short*)ws; ws += qk_elems * 2;
  unsigned short* vT    = (unsigned short*)ws; ws += v_elems * 2;
  float* msumb          = (float*)ws;          ws += (size_t)B_ * N_ * 4;

  convert_kernel<<<dim3((int)(w_elems / 2048)), 256, 0, stream>>>(Wq, Wqhi, Wqlo);
  convert_kernel<<<dim3((int)(w_elems / 2048)), 256, 0, stream>>>(Wk, Wkhi, Wklo);

  convert_kernel<<<dim3((int)(qk_elems / 2048)), 256, 0, stream>>>(q, Xhi, Xlo);
  proj_qk_kernel<<<dim3(64, 6), 256, 0, stream>>>(Xhi, Xlo, Wqhi, Wqlo,
                                                  qh_hi, qh_lo, K2E_);
  convert_kernel<<<dim3((int)(qk_elems / 2048)), 256, 0, stream>>>(k, Xhi, Xlo);
  proj_qk_kernel<<<dim3(64, 6), 256, 0, stream>>>(Xhi, Xlo, Wkhi, Wklo,
                                                  kh_hi, kh_lo, 1.0f);

  proj_v_kernel<<<dim3(128, 8), 256, 0, stream>>>(v, Wv, vT);
  msum_kernel<<<dim3(B_ * N_), 256, 0, stream>>>(masks, msumb);
  attn_kernel<<<dim3(H_, N_ / 128, B_), 256, 0, stream>>>(qh_hi, qh_lo, kh_hi, kh_lo,
                                                          vT, masks, msumb, out);
}